// Round 11
// baseline (142.334 us; speedup 1.0000x reference)
//
#include <hip/hip_runtime.h>
#include <stdint.h>

#define KSTEPS 24              // 768 / 32
#define TOKENS 16384           // B*S

typedef short short8 __attribute__((ext_vector_type(8)));
typedef float fx4 __attribute__((ext_vector_type(4)));
typedef unsigned short u16;
typedef u16 u16x4 __attribute__((ext_vector_type(4)));

static __device__ __forceinline__ u16 f2bf(float f) {
  union { float f; unsigned u; } v; v.f = f;
  return (u16)((v.u + 0x7fffu + ((v.u >> 16) & 1u)) >> 16);
}

static __device__ __forceinline__ fx4 mfma16(short8 a, short8 b, fx4 c) {
  return __builtin_amdgcn_mfma_f32_16x16x32_bf16(a, b, c, 0, 0, 0);
}

// async global->LDS, 16B/lane; lds dest = wave-uniform base + lane*16
static __device__ __forceinline__ void async16(const void* g, void* l) {
  __builtin_amdgcn_global_load_lds(
      (const __attribute__((address_space(1))) void*)g,
      (__attribute__((address_space(3))) void*)(unsigned int)(uintptr_t)l,
      16, 0, 0);
}

// ---------------- prep: W[768][64] fp32 (q,k,v) -> bf16 pre-fragmented B-operand layout
__global__ void prep_w_kernel(const float* __restrict__ Wq, const float* __restrict__ Wk,
                              const float* __restrict__ Wv, u16* __restrict__ wfrag) {
  int idx  = blockIdx.x * 256 + threadIdx.x;   // 72*256 = 18432 = 3*24*4*64
  int lane = idx & 63;
  int fid  = idx >> 6;
  int nt   = fid & 3;
  int ks   = (fid >> 2) % KSTEPS;
  int mat  = fid / (KSTEPS * 4);
  const float* W = (mat == 0) ? Wq : (mat == 1) ? Wk : Wv;
  int n  = nt * 16 + (lane & 15);
  int k0 = ks * 32 + (lane >> 4) * 8;
  short8 out;
#pragma unroll
  for (int j = 0; j < 8; j++) out[j] = (short)f2bf(W[(size_t)(k0 + j) * 64 + n]);
  *(short8*)(wfrag + (size_t)idx * 8) = out;
}

// ---------------- projection GEMM (LDS-staged, unchanged — control variable)
__global__ __launch_bounds__(256) void proj_kernel(const float* __restrict__ x,
                                                   const u16* __restrict__ wfrag,
                                                   u16* __restrict__ qb,
                                                   u16* __restrict__ kb,
                                                   u16* __restrict__ vT) {
  __shared__ float xs[2][32 * 32];    // [dbuf][tok][32 floats] chunk-swizzled
  __shared__ u16  Ws[2][12 * 512];    // [dbuf][f=(m*4+nt)][lane][8]

  int w = threadIdx.x >> 6, lane = threadIdx.x & 63;
  int ln = lane & 15, quad = lane >> 4;
  int rw = w >> 1, cs = w & 1;
  int s0 = blockIdx.x * 32;

  fx4 acc[6];
#pragma unroll
  for (int j = 0; j < 6; j++) acc[j] = (fx4){0.f, 0.f, 0.f, 0.f};

  int srow  = w * 8 + (lane >> 3);
  int slot  = lane & 7;
  int chunk = slot ^ (srow & 7);
  const float* xsrc = x + (size_t)(s0 + srow) * 768 + chunk * 4;

#pragma unroll
  for (int m = 0; m < 3; m++)
    async16(wfrag + ((size_t)(m * KSTEPS + 0) * 256 + w * 64 + lane) * 8,
            (char*)Ws[0] + m * 4096 + w * 1024 + lane * 16);
  async16(xsrc, (char*)xs[0] + w * 1024 + lane * 16);

  int r = rw * 16 + ln;
  for (int ks = 0; ks < KSTEPS; ks++) {
    __syncthreads();
    if (ks < KSTEPS - 1) {
      int buf = (ks + 1) & 1;
#pragma unroll
      for (int m = 0; m < 3; m++)
        async16(wfrag + ((size_t)(m * KSTEPS + ks + 1) * 256 + w * 64 + lane) * 8,
                (char*)Ws[buf] + m * 4096 + w * 1024 + lane * 16);
      async16(xsrc + (ks + 1) * 32, (char*)xs[buf] + w * 1024 + lane * 16);
    }
    const float* xb = xs[ks & 1];
    const u16*  wb = Ws[ks & 1];
    int sl0 = (2 * quad)     ^ (r & 7);
    int sl1 = (2 * quad + 1) ^ (r & 7);
    fx4 xa = *(const fx4*)(xb + r * 32 + sl0 * 4);
    fx4 xv = *(const fx4*)(xb + r * 32 + sl1 * 4);
    short8 af;
#pragma unroll
    for (int j = 0; j < 4; j++) { af[j] = (short)f2bf(xa[j]); af[4 + j] = (short)f2bf(xv[j]); }
#pragma unroll
    for (int j = 0; j < 6; j++) {
      short8 bf = *(const short8*)(wb + (cs * 6 + j) * 512 + lane * 8);
      acc[j] = mfma16(af, bf, acc[j]);
    }
  }

  int tok0 = s0 + rw * 16 + quad * 4;
#pragma unroll
  for (int j = 0; j < 6; j++) {
    int f = cs * 6 + j;
    int d = (f & 3) * 16 + ln;
    if (f < 4) {
      // Q pre-scaled by 0.125 * log2(e): scores land in exp2 domain
#pragma unroll
      for (int reg = 0; reg < 4; reg++)
        qb[(size_t)(tok0 + reg) * 64 + d] = f2bf(acc[j][reg] * 0.180336887f);
    } else if (f < 8) {
#pragma unroll
      for (int reg = 0; reg < 4; reg++)
        kb[(size_t)(tok0 + reg) * 64 + d] = f2bf(acc[j][reg]);
    } else {
      int b = tok0 >> 12, s = tok0 & 4095;
      u16x4 vp;
#pragma unroll
      for (int reg = 0; reg < 4; reg++) vp[reg] = f2bf(acc[j][reg]);
      *(u16x4*)(vT + ((size_t)b * 64 + d) * 4096 + s) = vp;
    }
  }
}

// ---------------- flash attention v7: BM=64, K+V DMA-staged dbuf; split-K 3-way
// so grid (64x4x3 = 768) == residency capacity (3 blocks/CU x 256 CUs): every
// block's serial chain runs concurrently start-to-finish. Static-max softmax.
__global__ __launch_bounds__(256) void attn_kernel(const u16* __restrict__ qb,
                                                   const u16* __restrict__ kb,
                                                   const u16* __restrict__ vT,
                                                   float* __restrict__ o0g,
                                                   float* __restrict__ po12,
                                                   float* __restrict__ mlb) {
  __shared__ u16 Kstg[2][4096];       // [buf][64 keys x 64 d]   16KB
  __shared__ u16 Vstg[2][4096];       // [buf][64 d x 64 keys]   16KB  (V^T layout)
  __shared__ u16 Ps[4][16 * 72];      // per-wave P round-trip, padded rows

  int w = threadIdx.x >> 6, lane = threadIdx.x & 63;
  int ln = lane & 15, quad = lane >> 4;
  int band = 63 - blockIdx.x;         // 64-row band, big workloads first
  int b = blockIdx.y, z = blockIdx.z; // batch, split-K third
  int q0 = band * 64;

  const u16* qbb = qb + (size_t)b * 4096 * 64;
  const u16* kbb = kb + (size_t)b * 4096 * 64;
  const u16* vtb = vT + (size_t)b * 64 * 4096;

  short8 qf0 = *(const short8*)(qbb + (size_t)(q0 + w * 16 + ln) * 64 + quad * 8);
  short8 qf1 = *(const short8*)(qbb + (size_t)(q0 + w * 16 + ln) * 64 + 32 + quad * 8);

  short8 ones;
#pragma unroll
  for (int j = 0; j < 8; j++) ones[j] = (short)0x3F80;   // bf16 1.0

  fx4 o[4];
#pragma unroll
  for (int nt2 = 0; nt2 < 4; nt2++) o[nt2] = (fx4){0.f, 0.f, 0.f, 0.f};
  float l_i[4] = {0.f, 0.f, 0.f, 0.f};

  int n = band + 1;                   // 64-key tiles this band needs
  int c = (n + 2) / 3;                // tiles per split-K third
  int lo = z * c; if (lo > n) lo = n;
  int hi = lo + c; if (hi > n) hi = n;

  // staging: tile = 64 rows x 128B = 512 x 16B chunks; 2 chunks/thread each,
  // XOR chunk-swizzled source. K row = key; V row = d (both contiguous global)
  if (lo < hi) {
#pragma unroll
    for (int j = 0; j < 2; j++) {
      int cc = (w * 2 + j) * 64 + lane;
      int row = cc >> 3, slot = cc & 7, sw = (slot ^ (row & 7)) * 8;
      async16(kbb + ((size_t)lo * 64 + row) * 64 + sw, (char*)Kstg[0] + (w * 2 + j) * 1024);
      async16(vtb + (size_t)row * 4096 + lo * 64 + sw, (char*)Vstg[0] + (w * 2 + j) * 1024);
    }
  }

  for (int t = lo; t < hi; t++) {
    __syncthreads();                  // publishes buf (t-lo)&1
    if (t + 1 < hi) {                 // prefetch next K+V tiles into other buf
      int nb = (t - lo + 1) & 1;
#pragma unroll
      for (int j = 0; j < 2; j++) {
        int cc = (w * 2 + j) * 64 + lane;
        int row = cc >> 3, slot = cc & 7, sw = (slot ^ (row & 7)) * 8;
        async16(kbb + ((size_t)(t + 1) * 64 + row) * 64 + sw,
                (char*)Kstg[nb] + (w * 2 + j) * 1024);
        async16(vtb + (size_t)row * 4096 + (t + 1) * 64 + sw,
                (char*)Vstg[nb] + (w * 2 + j) * 1024);
      }
    }
    const u16* Kb = Kstg[(t - lo) & 1];
    const u16* Vb = Vstg[(t - lo) & 1];

    fx4 sA[4];
#pragma unroll
    for (int nt = 0; nt < 4; nt++) {
      int row = nt * 16 + ln;
      int s0_ = quad ^ (row & 7), s1_ = (quad + 4) ^ (row & 7);
      short8 kf0 = *(const short8*)(Kb + (row * 8 + s0_) * 8);
      short8 kf1 = *(const short8*)(Kb + (row * 8 + s1_) * 8);
      sA[nt] = mfma16(qf0, kf0, (fx4){0.f, 0.f, 0.f, 0.f});
      sA[nt] = mfma16(qf1, kf1, sA[nt]);
    }

    if (t == n - 1) {  // diagonal tile mask
#pragma unroll
      for (int nt = 0; nt < 4; nt++)
#pragma unroll
        for (int reg = 0; reg < 4; reg++) {
          int col = t * 64 + nt * 16 + ln;
          int rowg = q0 + w * 16 + quad * 4 + reg;
          if (col > rowg) sA[nt][reg] = -1e30f;
        }
    }

    // static max: p = 2^s (normalizer cancels); C-layout -> A-layout via LDS
#pragma unroll
    for (int nt = 0; nt < 4; nt++)
#pragma unroll
      for (int reg = 0; reg < 4; reg++)
        Ps[w][(quad * 4 + reg) * 72 + nt * 16 + ln] =
            f2bf(__builtin_amdgcn_exp2f(sA[nt][reg]));

    short8 pf0 = *(const short8*)(&Ps[w][ln * 72 + quad * 8]);
    short8 pf1 = *(const short8*)(&Ps[w][ln * 72 + 32 + quad * 8]);

    // row-sum of P via MFMA with ones-B
    fx4 lacc = mfma16(pf0, ones, (fx4){0.f, 0.f, 0.f, 0.f});
    lacc = mfma16(pf1, ones, lacc);
#pragma unroll
    for (int reg = 0; reg < 4; reg++) l_i[reg] += lacc[reg];

    // PV: V B-frag from LDS V^T tile
#pragma unroll
    for (int nt2 = 0; nt2 < 4; nt2++) {
      int row = nt2 * 16 + ln;
      int s0_ = quad ^ (row & 7), s1_ = (quad + 4) ^ (row & 7);
      short8 vf0 = *(const short8*)(Vb + (row * 8 + s0_) * 8);
      short8 vf1 = *(const short8*)(Vb + (row * 8 + s1_) * 8);
      o[nt2] = mfma16(pf0, vf0, o[nt2]);
      o[nt2] = mfma16(pf1, vf1, o[nt2]);
    }
  }

  // write unnormalized partial + l; each wave owns its 16 rows (no merge barrier)
  float* dst = (z == 0) ? o0g : (po12 + (size_t)(z - 1) * 4 * 4096 * 64);
#pragma unroll
  for (int nt2 = 0; nt2 < 4; nt2++)
#pragma unroll
    for (int reg = 0; reg < 4; reg++) {
      int rowg = q0 + w * 16 + quad * 4 + reg;
      dst[((size_t)b * 4096 + rowg) * 64 + nt2 * 16 + ln] = o[nt2][reg];
    }
  if (ln == 0) {
#pragma unroll
    for (int reg = 0; reg < 4; reg++) {
      int rowg = q0 + w * 16 + quad * 4 + reg;
      mlb[((size_t)z * 4 + b) * 4096 + rowg] = l_i[reg];
    }
  }
}

// ---------------- merge the three split-K thirds: out = Σo_z / Σl_z
__global__ __launch_bounds__(256) void merge_kernel(float* __restrict__ out,
                                                    const float* __restrict__ po12,
                                                    const float* __restrict__ mlb) {
  int qt = blockIdx.x, b = blockIdx.y;
  int r = threadIdx.x >> 3;
  int c = (threadIdx.x & 7) * 8;
  size_t row = (size_t)b * 4096 + qt * 32 + r;
  float l = mlb[row];
#pragma unroll
  for (int z = 1; z < 3; z++) l += mlb[(size_t)z * 4 * 4096 + row];
  float inv = 1.0f / l;
  float* op = out + row * 64 + c;
  fx4 u0 = *(fx4*)op, u1 = *(fx4*)(op + 4);
#pragma unroll
  for (int z = 1; z < 3; z++) {
    const float* pp = po12 + (size_t)(z - 1) * 4 * 4096 * 64 + row * 64 + c;
    fx4 v0 = *(const fx4*)pp, v1 = *(const fx4*)(pp + 4);
#pragma unroll
    for (int j = 0; j < 4; j++) { u0[j] += v0[j]; u1[j] += v1[j]; }
  }
#pragma unroll
  for (int j = 0; j < 4; j++) { u0[j] *= inv; u1[j] *= inv; }
  *(fx4*)op = u0;
  *(fx4*)(op + 4) = u1;
}

extern "C" void kernel_launch(void* const* d_in, const int* in_sizes, int n_in,
                              void* d_out, int out_size, void* d_ws, size_t ws_size,
                              hipStream_t stream) {
  const float* x  = (const float*)d_in[0];
  const float* Wq = (const float*)d_in[1];
  const float* Wk = (const float*)d_in[2];
  const float* Wv = (const float*)d_in[3];

  u16* qbw = (u16*)d_ws;                          // [16384][64] bf16, 2MB
  u16* kbw = qbw + (size_t)TOKENS * 64;           // 2MB
  u16* vtw = kbw + (size_t)TOKENS * 64;           // 2MB
  u16* wfr = vtw + (size_t)TOKENS * 64;           // 288KB
  float* po12 = (float*)(wfr + (size_t)3 * KSTEPS * 256 * 8);  // 2x [4][4096][64] fp32, 8MB
  float* mlb = po12 + (size_t)2 * 4 * 4096 * 64;  // [3][4][4096] float, 192KB

  prep_w_kernel<<<72, 256, 0, stream>>>(Wq, Wk, Wv, wfr);
  proj_kernel<<<TOKENS / 32, 256, 0, stream>>>(x, wfr, qbw, kbw, vtw);
  attn_kernel<<<dim3(64, 4, 3), 256, 0, stream>>>(qbw, kbw, vtw,
                                                  (float*)d_out, po12, mlb);
  merge_kernel<<<dim3(128, 4), 256, 0, stream>>>((float*)d_out, po12, mlb);
}

// Round 12
// 138.569 us; speedup vs baseline: 1.0272x; 1.0272x over previous
//
#include <hip/hip_runtime.h>
#include <stdint.h>

#define KSTEPS 24              // 768 / 32
#define TOKENS 16384           // B*S

typedef short short8 __attribute__((ext_vector_type(8)));
typedef float fx4 __attribute__((ext_vector_type(4)));
typedef unsigned short u16;
typedef u16 u16x4 __attribute__((ext_vector_type(4)));

static __device__ __forceinline__ u16 f2bf(float f) {
  union { float f; unsigned u; } v; v.f = f;
  return (u16)((v.u + 0x7fffu + ((v.u >> 16) & 1u)) >> 16);
}

// cheap round (half-up) for the attention hot loop: p is post-exp2, tolerance-safe
static __device__ __forceinline__ u16 p2bf(float f) {
  union { float f; unsigned u; } v; v.f = f;
  return (u16)((v.u + 0x8000u) >> 16);
}

static __device__ __forceinline__ fx4 mfma16(short8 a, short8 b, fx4 c) {
  return __builtin_amdgcn_mfma_f32_16x16x32_bf16(a, b, c, 0, 0, 0);
}

// async global->LDS, 16B/lane; lds dest = wave-uniform base + lane*16
static __device__ __forceinline__ void async16(const void* g, void* l) {
  __builtin_amdgcn_global_load_lds(
      (const __attribute__((address_space(1))) void*)g,
      (__attribute__((address_space(3))) void*)(unsigned int)(uintptr_t)l,
      16, 0, 0);
}

// ---------------- prep: W[768][64] fp32 (q,k,v) -> bf16 pre-fragmented B-operand layout
__global__ void prep_w_kernel(const float* __restrict__ Wq, const float* __restrict__ Wk,
                              const float* __restrict__ Wv, u16* __restrict__ wfrag) {
  int idx  = blockIdx.x * 256 + threadIdx.x;   // 72*256 = 18432 = 3*24*4*64
  int lane = idx & 63;
  int fid  = idx >> 6;
  int nt   = fid & 3;
  int ks   = (fid >> 2) % KSTEPS;
  int mat  = fid / (KSTEPS * 4);
  const float* W = (mat == 0) ? Wq : (mat == 1) ? Wk : Wv;
  int n  = nt * 16 + (lane & 15);
  int k0 = ks * 32 + (lane >> 4) * 8;
  short8 out;
#pragma unroll
  for (int j = 0; j < 8; j++) out[j] = (short)f2bf(W[(size_t)(k0 + j) * 64 + n]);
  *(short8*)(wfrag + (size_t)idx * 8) = out;
}

// ---------------- projection GEMM (LDS-staged, unchanged — control variable)
__global__ __launch_bounds__(256) void proj_kernel(const float* __restrict__ x,
                                                   const u16* __restrict__ wfrag,
                                                   u16* __restrict__ qb,
                                                   u16* __restrict__ kb,
                                                   u16* __restrict__ vT) {
  __shared__ float xs[2][32 * 32];    // [dbuf][tok][32 floats] chunk-swizzled
  __shared__ u16  Ws[2][12 * 512];    // [dbuf][f=(m*4+nt)][lane][8]

  int w = threadIdx.x >> 6, lane = threadIdx.x & 63;
  int ln = lane & 15, quad = lane >> 4;
  int rw = w >> 1, cs = w & 1;
  int s0 = blockIdx.x * 32;

  fx4 acc[6];
#pragma unroll
  for (int j = 0; j < 6; j++) acc[j] = (fx4){0.f, 0.f, 0.f, 0.f};

  int srow  = w * 8 + (lane >> 3);
  int slot  = lane & 7;
  int chunk = slot ^ (srow & 7);
  const float* xsrc = x + (size_t)(s0 + srow) * 768 + chunk * 4;

#pragma unroll
  for (int m = 0; m < 3; m++)
    async16(wfrag + ((size_t)(m * KSTEPS + 0) * 256 + w * 64 + lane) * 8,
            (char*)Ws[0] + m * 4096 + w * 1024 + lane * 16);
  async16(xsrc, (char*)xs[0] + w * 1024 + lane * 16);

  int r = rw * 16 + ln;
  for (int ks = 0; ks < KSTEPS; ks++) {
    __syncthreads();
    if (ks < KSTEPS - 1) {
      int buf = (ks + 1) & 1;
#pragma unroll
      for (int m = 0; m < 3; m++)
        async16(wfrag + ((size_t)(m * KSTEPS + ks + 1) * 256 + w * 64 + lane) * 8,
                (char*)Ws[buf] + m * 4096 + w * 1024 + lane * 16);
      async16(xsrc + (ks + 1) * 32, (char*)xs[buf] + w * 1024 + lane * 16);
    }
    const float* xb = xs[ks & 1];
    const u16*  wb = Ws[ks & 1];
    int sl0 = (2 * quad)     ^ (r & 7);
    int sl1 = (2 * quad + 1) ^ (r & 7);
    fx4 xa = *(const fx4*)(xb + r * 32 + sl0 * 4);
    fx4 xv = *(const fx4*)(xb + r * 32 + sl1 * 4);
    short8 af;
#pragma unroll
    for (int j = 0; j < 4; j++) { af[j] = (short)f2bf(xa[j]); af[4 + j] = (short)f2bf(xv[j]); }
#pragma unroll
    for (int j = 0; j < 6; j++) {
      short8 bf = *(const short8*)(wb + (cs * 6 + j) * 512 + lane * 8);
      acc[j] = mfma16(af, bf, acc[j]);
    }
  }

  int tok0 = s0 + rw * 16 + quad * 4;
#pragma unroll
  for (int j = 0; j < 6; j++) {
    int f = cs * 6 + j;
    int d = (f & 3) * 16 + ln;
    if (f < 4) {
      // Q pre-scaled by 0.125 * log2(e): scores land in exp2 domain
#pragma unroll
      for (int reg = 0; reg < 4; reg++)
        qb[(size_t)(tok0 + reg) * 64 + d] = f2bf(acc[j][reg] * 0.180336887f);
    } else if (f < 8) {
#pragma unroll
      for (int reg = 0; reg < 4; reg++)
        kb[(size_t)(tok0 + reg) * 64 + d] = f2bf(acc[j][reg]);
    } else {
      int b = tok0 >> 12, s = tok0 & 4095;
      u16x4 vp;
#pragma unroll
      for (int reg = 0; reg < 4; reg++) vp[reg] = f2bf(acc[j][reg]);
      *(u16x4*)(vT + ((size_t)b * 64 + d) * 4096 + s) = vp;
    }
  }
}

// ---------------- flash attention v8: BM=128, 8 waves/block (512 thr) share one
// staged K/V tile -> 24 waves/CU (6 chains/SIMD). Split-K 6-way, grid 32x4x6 =
// 768 blocks = exact residency. Static-max softmax (p = 2^s, partials additive).
__global__ __launch_bounds__(512) void attn_kernel(const u16* __restrict__ qb,
                                                   const u16* __restrict__ kb,
                                                   const u16* __restrict__ vT,
                                                   float* __restrict__ o0g,
                                                   float* __restrict__ po5,
                                                   float* __restrict__ mlb) {
  __shared__ u16 Kstg[2][4096];       // [buf][64 keys x 64 d]   16KB
  __shared__ u16 Vstg[2][4096];       // [buf][64 d x 64 keys]   16KB  (V^T layout)
  __shared__ u16 Ps[8][16 * 72];      // per-wave P round-trip, padded rows 18KB

  int w = threadIdx.x >> 6, lane = threadIdx.x & 63;
  int ln = lane & 15, quad = lane >> 4;
  int band = 31 - blockIdx.x;         // 128-row band
  int b = blockIdx.y, z = blockIdx.z; // batch, split-K sixth
  int q0 = band * 128;
  int qw = q0 + w * 16;               // this wave's first Q-row

  const u16* qbb = qb + (size_t)b * 4096 * 64;
  const u16* kbb = kb + (size_t)b * 4096 * 64;
  const u16* vtb = vT + (size_t)b * 64 * 4096;

  short8 qf0 = *(const short8*)(qbb + (size_t)(qw + ln) * 64 + quad * 8);
  short8 qf1 = *(const short8*)(qbb + (size_t)(qw + ln) * 64 + 32 + quad * 8);

  short8 ones;
#pragma unroll
  for (int j = 0; j < 8; j++) ones[j] = (short)0x3F80;   // bf16 1.0

  fx4 o[4];
#pragma unroll
  for (int nt2 = 0; nt2 < 4; nt2++) o[nt2] = (fx4){0.f, 0.f, 0.f, 0.f};
  float l_i[4] = {0.f, 0.f, 0.f, 0.f};

  int n = 2 * band + 2;               // 64-key tiles this band needs
  int c = (n + 5) / 6;                // tiles per split-K sixth
  int lo = z * c; if (lo > n) lo = n;
  int hi = lo + c; if (hi > n) hi = n;

  // staging: tile = 512 x 16B chunks; 512 threads -> 1 K-chunk + 1 V-chunk each
  int cc = w * 64 + lane;
  int srow = cc >> 3, sslot = cc & 7, sw_ = (sslot ^ (srow & 7)) * 8;
  if (lo < hi) {
    async16(kbb + ((size_t)lo * 64 + srow) * 64 + sw_, (char*)Kstg[0] + cc * 16);
    async16(vtb + (size_t)srow * 4096 + lo * 64 + sw_, (char*)Vstg[0] + cc * 16);
  }

  for (int t = lo; t < hi; t++) {
    __syncthreads();                  // publishes buf (t-lo)&1
    if (t + 1 < hi) {                 // prefetch next K+V tiles into other buf
      int nb = (t - lo + 1) & 1;
      async16(kbb + ((size_t)(t + 1) * 64 + srow) * 64 + sw_, (char*)Kstg[nb] + cc * 16);
      async16(vtb + (size_t)srow * 4096 + (t + 1) * 64 + sw_, (char*)Vstg[nb] + cc * 16);
    }
    if (64 * t > qw + 15) continue;   // tile entirely above diagonal for this wave

    const u16* Kb = Kstg[(t - lo) & 1];
    const u16* Vb = Vstg[(t - lo) & 1];

    fx4 sA[4];
#pragma unroll
    for (int nt = 0; nt < 4; nt++) {
      int row = nt * 16 + ln;
      int s0_ = quad ^ (row & 7), s1_ = (quad + 4) ^ (row & 7);
      short8 kf0 = *(const short8*)(Kb + (row * 8 + s0_) * 8);
      short8 kf1 = *(const short8*)(Kb + (row * 8 + s1_) * 8);
      sA[nt] = mfma16(qf0, kf0, (fx4){0.f, 0.f, 0.f, 0.f});
      sA[nt] = mfma16(qf1, kf1, sA[nt]);
    }

    if (64 * t + 63 > qw) {           // diagonal-overlapping tile: mask
#pragma unroll
      for (int nt = 0; nt < 4; nt++)
#pragma unroll
        for (int reg = 0; reg < 4; reg++) {
          int col = t * 64 + nt * 16 + ln;
          int rowg = qw + quad * 4 + reg;
          if (col > rowg) sA[nt][reg] = -1e30f;
        }
    }

    // static max: p = 2^s (normalizer cancels); C-layout -> A-layout via LDS
#pragma unroll
    for (int nt = 0; nt < 4; nt++)
#pragma unroll
      for (int reg = 0; reg < 4; reg++)
        Ps[w][(quad * 4 + reg) * 72 + nt * 16 + ln] =
            p2bf(__builtin_amdgcn_exp2f(sA[nt][reg]));

    short8 pf0 = *(const short8*)(&Ps[w][ln * 72 + quad * 8]);
    short8 pf1 = *(const short8*)(&Ps[w][ln * 72 + 32 + quad * 8]);

    // row-sum of P via MFMA with ones-B
    fx4 lacc = mfma16(pf0, ones, (fx4){0.f, 0.f, 0.f, 0.f});
    lacc = mfma16(pf1, ones, lacc);
#pragma unroll
    for (int reg = 0; reg < 4; reg++) l_i[reg] += lacc[reg];

    // PV: V B-frag from LDS V^T tile
#pragma unroll
    for (int nt2 = 0; nt2 < 4; nt2++) {
      int row = nt2 * 16 + ln;
      int s0_ = quad ^ (row & 7), s1_ = (quad + 4) ^ (row & 7);
      short8 vf0 = *(const short8*)(Vb + (row * 8 + s0_) * 8);
      short8 vf1 = *(const short8*)(Vb + (row * 8 + s1_) * 8);
      o[nt2] = mfma16(pf0, vf0, o[nt2]);
      o[nt2] = mfma16(pf1, vf1, o[nt2]);
    }
  }

  // write unnormalized partial + l; each wave owns its 16 rows
  float* dst = (z == 0) ? o0g : (po5 + (size_t)(z - 1) * 4 * 4096 * 64);
#pragma unroll
  for (int nt2 = 0; nt2 < 4; nt2++)
#pragma unroll
    for (int reg = 0; reg < 4; reg++) {
      int rowg = qw + quad * 4 + reg;
      dst[((size_t)b * 4096 + rowg) * 64 + nt2 * 16 + ln] = o[nt2][reg];
    }
  if (ln == 0) {
#pragma unroll
    for (int reg = 0; reg < 4; reg++) {
      int rowg = qw + quad * 4 + reg;
      mlb[((size_t)z * 4 + b) * 4096 + rowg] = l_i[reg];
    }
  }
}

// ---------------- merge the six split-K parts: out = Σo_z / Σl_z
__global__ __launch_bounds__(256) void merge_kernel(float* __restrict__ out,
                                                    const float* __restrict__ po5,
                                                    const float* __restrict__ mlb) {
  int qt = blockIdx.x, b = blockIdx.y;
  int r = threadIdx.x >> 3;
  int c = (threadIdx.x & 7) * 8;
  size_t row = (size_t)b * 4096 + qt * 32 + r;
  float l = mlb[row];
#pragma unroll
  for (int z = 1; z < 6; z++) l += mlb[(size_t)z * 4 * 4096 + row];
  float inv = 1.0f / l;
  float* op = out + row * 64 + c;
  fx4 u0 = *(fx4*)op, u1 = *(fx4*)(op + 4);
#pragma unroll
  for (int z = 1; z < 6; z++) {
    const float* pp = po5 + (size_t)(z - 1) * 4 * 4096 * 64 + row * 64 + c;
    fx4 v0 = *(const fx4*)pp, v1 = *(const fx4*)(pp + 4);
#pragma unroll
    for (int j = 0; j < 4; j++) { u0[j] += v0[j]; u1[j] += v1[j]; }
  }
#pragma unroll
  for (int j = 0; j < 4; j++) { u0[j] *= inv; u1[j] *= inv; }
  *(fx4*)op = u0;
  *(fx4*)(op + 4) = u1;
}

extern "C" void kernel_launch(void* const* d_in, const int* in_sizes, int n_in,
                              void* d_out, int out_size, void* d_ws, size_t ws_size,
                              hipStream_t stream) {
  const float* x  = (const float*)d_in[0];
  const float* Wq = (const float*)d_in[1];
  const float* Wk = (const float*)d_in[2];
  const float* Wv = (const float*)d_in[3];

  u16* qbw = (u16*)d_ws;                          // [16384][64] bf16, 2MB
  u16* kbw = qbw + (size_t)TOKENS * 64;           // 2MB
  u16* vtw = kbw + (size_t)TOKENS * 64;           // 2MB
  u16* wfr = vtw + (size_t)TOKENS * 64;           // 288KB
  float* po5 = (float*)(wfr + (size_t)3 * KSTEPS * 256 * 8);  // 5x [4][4096][64] fp32, 20MB
  float* mlb = po5 + (size_t)5 * 4 * 4096 * 64;   // [6][4][4096] float, 384KB

  prep_w_kernel<<<72, 256, 0, stream>>>(Wq, Wk, Wv, wfr);
  proj_kernel<<<TOKENS / 32, 256, 0, stream>>>(x, wfr, qbw, kbw, vtw);
  attn_kernel<<<dim3(32, 4, 6), 512, 0, stream>>>(qbw, kbw, vtw,
                                                  (float*)d_out, po5, mlb);
  merge_kernel<<<dim3(128, 4), 256, 0, stream>>>((float*)d_out, po5, mlb);
}

// Round 13
// 136.559 us; speedup vs baseline: 1.0423x; 1.0147x over previous
//
#include <hip/hip_runtime.h>
#include <stdint.h>

#define KSTEPS 24              // 768 / 32
#define TOKENS 16384           // B*S

typedef short short8 __attribute__((ext_vector_type(8)));
typedef float fx4 __attribute__((ext_vector_type(4)));
typedef unsigned short u16;
typedef u16 u16x4 __attribute__((ext_vector_type(4)));

static __device__ __forceinline__ u16 f2bf(float f) {
  union { float f; unsigned u; } v; v.f = f;
  return (u16)((v.u + 0x7fffu + ((v.u >> 16) & 1u)) >> 16);
}

// cheap round (half-up) for the attention hot loop: p is post-exp2, tolerance-safe
static __device__ __forceinline__ u16 p2bf(float f) {
  union { float f; unsigned u; } v; v.f = f;
  return (u16)((v.u + 0x8000u) >> 16);
}

static __device__ __forceinline__ fx4 mfma16(short8 a, short8 b, fx4 c) {
  return __builtin_amdgcn_mfma_f32_16x16x32_bf16(a, b, c, 0, 0, 0);
}

// async global->LDS, 16B/lane; lds dest = wave-uniform base + lane*16
static __device__ __forceinline__ void async16(const void* g, void* l) {
  __builtin_amdgcn_global_load_lds(
      (const __attribute__((address_space(1))) void*)g,
      (__attribute__((address_space(3))) void*)(unsigned int)(uintptr_t)l,
      16, 0, 0);
}

// ---------------- prep: W[768][64] fp32 (q,k,v) -> bf16 pre-fragmented B-operand layout
__global__ void prep_w_kernel(const float* __restrict__ Wq, const float* __restrict__ Wk,
                              const float* __restrict__ Wv, u16* __restrict__ wfrag) {
  int idx  = blockIdx.x * 256 + threadIdx.x;   // 72*256 = 18432 = 3*24*4*64
  int lane = idx & 63;
  int fid  = idx >> 6;
  int nt   = fid & 3;
  int ks   = (fid >> 2) % KSTEPS;
  int mat  = fid / (KSTEPS * 4);
  const float* W = (mat == 0) ? Wq : (mat == 1) ? Wk : Wv;
  int n  = nt * 16 + (lane & 15);
  int k0 = ks * 32 + (lane >> 4) * 8;
  short8 out;
#pragma unroll
  for (int j = 0; j < 8; j++) out[j] = (short)f2bf(W[(size_t)(k0 + j) * 64 + n]);
  *(short8*)(wfrag + (size_t)idx * 8) = out;
}

// ---------------- projection GEMM (LDS-staged, unchanged — control variable)
__global__ __launch_bounds__(256) void proj_kernel(const float* __restrict__ x,
                                                   const u16* __restrict__ wfrag,
                                                   u16* __restrict__ qb,
                                                   u16* __restrict__ kb,
                                                   u16* __restrict__ vT) {
  __shared__ float xs[2][32 * 32];    // [dbuf][tok][32 floats] chunk-swizzled
  __shared__ u16  Ws[2][12 * 512];    // [dbuf][f=(m*4+nt)][lane][8]

  int w = threadIdx.x >> 6, lane = threadIdx.x & 63;
  int ln = lane & 15, quad = lane >> 4;
  int rw = w >> 1, cs = w & 1;
  int s0 = blockIdx.x * 32;

  fx4 acc[6];
#pragma unroll
  for (int j = 0; j < 6; j++) acc[j] = (fx4){0.f, 0.f, 0.f, 0.f};

  int srow  = w * 8 + (lane >> 3);
  int slot  = lane & 7;
  int chunk = slot ^ (srow & 7);
  const float* xsrc = x + (size_t)(s0 + srow) * 768 + chunk * 4;

#pragma unroll
  for (int m = 0; m < 3; m++)
    async16(wfrag + ((size_t)(m * KSTEPS + 0) * 256 + w * 64 + lane) * 8,
            (char*)Ws[0] + m * 4096 + w * 1024 + lane * 16);
  async16(xsrc, (char*)xs[0] + w * 1024 + lane * 16);

  int r = rw * 16 + ln;
  for (int ks = 0; ks < KSTEPS; ks++) {
    __syncthreads();
    if (ks < KSTEPS - 1) {
      int buf = (ks + 1) & 1;
#pragma unroll
      for (int m = 0; m < 3; m++)
        async16(wfrag + ((size_t)(m * KSTEPS + ks + 1) * 256 + w * 64 + lane) * 8,
                (char*)Ws[buf] + m * 4096 + w * 1024 + lane * 16);
      async16(xsrc + (ks + 1) * 32, (char*)xs[buf] + w * 1024 + lane * 16);
    }
    const float* xb = xs[ks & 1];
    const u16*  wb = Ws[ks & 1];
    int sl0 = (2 * quad)     ^ (r & 7);
    int sl1 = (2 * quad + 1) ^ (r & 7);
    fx4 xa = *(const fx4*)(xb + r * 32 + sl0 * 4);
    fx4 xv = *(const fx4*)(xb + r * 32 + sl1 * 4);
    short8 af;
#pragma unroll
    for (int j = 0; j < 4; j++) { af[j] = (short)f2bf(xa[j]); af[4 + j] = (short)f2bf(xv[j]); }
#pragma unroll
    for (int j = 0; j < 6; j++) {
      short8 bf = *(const short8*)(wb + (cs * 6 + j) * 512 + lane * 8);
      acc[j] = mfma16(af, bf, acc[j]);
    }
  }

  int tok0 = s0 + rw * 16 + quad * 4;
#pragma unroll
  for (int j = 0; j < 6; j++) {
    int f = cs * 6 + j;
    int d = (f & 3) * 16 + ln;
    if (f < 4) {
      // Q pre-scaled by 0.125 * log2(e): scores land in exp2 domain
#pragma unroll
      for (int reg = 0; reg < 4; reg++)
        qb[(size_t)(tok0 + reg) * 64 + d] = f2bf(acc[j][reg] * 0.180336887f);
    } else if (f < 8) {
#pragma unroll
      for (int reg = 0; reg < 4; reg++)
        kb[(size_t)(tok0 + reg) * 64 + d] = f2bf(acc[j][reg]);
    } else {
      int b = tok0 >> 12, s = tok0 & 4095;
      u16x4 vp;
#pragma unroll
      for (int reg = 0; reg < 4; reg++) vp[reg] = f2bf(acc[j][reg]);
      *(u16x4*)(vT + ((size_t)b * 64 + d) * 4096 + s) = vp;
    }
  }
}

// ---------------- flash attention v9: each wave owns 32 Q-rows (two 16-row
// A-tiles) so every K/V ds_read_b128 feeds TWO MFMAs — LDS-pipe cycles per
// unit work cut ~1.5x (the measured bottleneck). BM=128, 4 waves, 256 thr;
// K+V DMA-staged dbuf; split-K 6-way; grid 32x4x6 = 768 = exact residency.
__global__ __launch_bounds__(256, 3) void attn_kernel(const u16* __restrict__ qb,
                                                      const u16* __restrict__ kb,
                                                      const u16* __restrict__ vT,
                                                      float* __restrict__ o0g,
                                                      float* __restrict__ po5,
                                                      float* __restrict__ mlb) {
  __shared__ u16 Kstg[2][4096];       // [buf][64 keys x 64 d]   16KB
  __shared__ u16 Vstg[2][4096];       // [buf][64 d x 64 keys]   16KB (V^T)
  __shared__ u16 Ps[4][32 * 72];      // per-wave P (32 rows), padded: 18KB

  int w = threadIdx.x >> 6, lane = threadIdx.x & 63;
  int ln = lane & 15, quad = lane >> 4;
  int band = 31 - blockIdx.x;         // 128-row band
  int b = blockIdx.y, z = blockIdx.z; // batch, split-K sixth
  int q0 = band * 128;
  int qw = q0 + w * 32;               // this wave's first Q-row (owns 32 rows)

  const u16* qbb = qb + (size_t)b * 4096 * 64;
  const u16* kbb = kb + (size_t)b * 4096 * 64;
  const u16* vtb = vT + (size_t)b * 64 * 4096;

  // Q A-frags for both 16-row tiles
  short8 qf0a = *(const short8*)(qbb + (size_t)(qw + ln) * 64 + quad * 8);
  short8 qf1a = *(const short8*)(qbb + (size_t)(qw + ln) * 64 + 32 + quad * 8);
  short8 qf0b = *(const short8*)(qbb + (size_t)(qw + 16 + ln) * 64 + quad * 8);
  short8 qf1b = *(const short8*)(qbb + (size_t)(qw + 16 + ln) * 64 + 32 + quad * 8);

  short8 ones;
#pragma unroll
  for (int j = 0; j < 8; j++) ones[j] = (short)0x3F80;   // bf16 1.0

  fx4 oa[4], ob[4];
#pragma unroll
  for (int j = 0; j < 4; j++) { oa[j] = (fx4){0.f,0.f,0.f,0.f}; ob[j] = (fx4){0.f,0.f,0.f,0.f}; }
  float la[4] = {0.f,0.f,0.f,0.f}, lb[4] = {0.f,0.f,0.f,0.f};

  int n = 2 * band + 2;               // 64-key tiles this band needs
  int c = (n + 5) / 6;                // tiles per split-K sixth
  int lo = z * c; if (lo > n) lo = n;
  int hi = lo + c; if (hi > n) hi = n;

  // staging: 512 chunks per tile; 256 threads x 2 chunks each (K and V)
  int t0c = w * 64 + lane;
  if (lo < hi) {
#pragma unroll
    for (int j = 0; j < 2; j++) {
      int cc = t0c + j * 256;
      int row = cc >> 3, slot = cc & 7, sw_ = (slot ^ (row & 7)) * 8;
      async16(kbb + ((size_t)lo * 64 + row) * 64 + sw_, (char*)Kstg[0] + cc * 16);
      async16(vtb + (size_t)row * 4096 + lo * 64 + sw_, (char*)Vstg[0] + cc * 16);
    }
  }

  for (int t = lo; t < hi; t++) {
    __syncthreads();                  // publishes buf (t-lo)&1
    if (t + 1 < hi) {                 // prefetch next K+V tiles into other buf
      int nb = (t - lo + 1) & 1;
#pragma unroll
      for (int j = 0; j < 2; j++) {
        int cc = t0c + j * 256;
        int row = cc >> 3, slot = cc & 7, sw_ = (slot ^ (row & 7)) * 8;
        async16(kbb + ((size_t)(t + 1) * 64 + row) * 64 + sw_, (char*)Kstg[nb] + cc * 16);
        async16(vtb + (size_t)row * 4096 + (t + 1) * 64 + sw_, (char*)Vstg[nb] + cc * 16);
      }
    }
    if (64 * t > qw + 31) continue;   // tile entirely above this wave's rows

    const u16* Kb = Kstg[(t - lo) & 1];
    const u16* Vb = Vstg[(t - lo) & 1];

    // QK for both row-tiles: each kf read feeds 2 MFMAs
    fx4 sAa[4], sAb[4];
#pragma unroll
    for (int nt = 0; nt < 4; nt++) {
      int row = nt * 16 + ln;
      int s0_ = quad ^ (row & 7), s1_ = (quad + 4) ^ (row & 7);
      short8 kf0 = *(const short8*)(Kb + (row * 8 + s0_) * 8);
      short8 kf1 = *(const short8*)(Kb + (row * 8 + s1_) * 8);
      sAa[nt] = mfma16(qf0a, kf0, (fx4){0.f,0.f,0.f,0.f});
      sAa[nt] = mfma16(qf1a, kf1, sAa[nt]);
      sAb[nt] = mfma16(qf0b, kf0, (fx4){0.f,0.f,0.f,0.f});
      sAb[nt] = mfma16(qf1b, kf1, sAb[nt]);
    }

    if (64 * t + 63 > qw) {           // diagonal-overlapping: mask both tiles
#pragma unroll
      for (int nt = 0; nt < 4; nt++)
#pragma unroll
        for (int reg = 0; reg < 4; reg++) {
          int col = t * 64 + nt * 16 + ln;
          int ra = qw + quad * 4 + reg;
          if (col > ra) sAa[nt][reg] = -1e30f;
          if (col > ra + 16) sAb[nt][reg] = -1e30f;
        }
    }

    // static max: p = 2^s; C-layout -> A-layout via LDS (32 rows per wave)
#pragma unroll
    for (int nt = 0; nt < 4; nt++)
#pragma unroll
      for (int reg = 0; reg < 4; reg++) {
        Ps[w][(quad * 4 + reg) * 72 + nt * 16 + ln] =
            p2bf(__builtin_amdgcn_exp2f(sAa[nt][reg]));
        Ps[w][(16 + quad * 4 + reg) * 72 + nt * 16 + ln] =
            p2bf(__builtin_amdgcn_exp2f(sAb[nt][reg]));
      }

    short8 pf0a = *(const short8*)(&Ps[w][ln * 72 + quad * 8]);
    short8 pf1a = *(const short8*)(&Ps[w][ln * 72 + 32 + quad * 8]);
    short8 pf0b = *(const short8*)(&Ps[w][(16 + ln) * 72 + quad * 8]);
    short8 pf1b = *(const short8*)(&Ps[w][(16 + ln) * 72 + 32 + quad * 8]);

    // row-sums via MFMA with ones-B
    fx4 lacc = mfma16(pf0a, ones, (fx4){0.f,0.f,0.f,0.f});
    lacc = mfma16(pf1a, ones, lacc);
#pragma unroll
    for (int reg = 0; reg < 4; reg++) la[reg] += lacc[reg];
    lacc = mfma16(pf0b, ones, (fx4){0.f,0.f,0.f,0.f});
    lacc = mfma16(pf1b, ones, lacc);
#pragma unroll
    for (int reg = 0; reg < 4; reg++) lb[reg] += lacc[reg];

    // PV: each vf read feeds 2 MFMAs
#pragma unroll
    for (int nt2 = 0; nt2 < 4; nt2++) {
      int row = nt2 * 16 + ln;
      int s0_ = quad ^ (row & 7), s1_ = (quad + 4) ^ (row & 7);
      short8 vf0 = *(const short8*)(Vb + (row * 8 + s0_) * 8);
      short8 vf1 = *(const short8*)(Vb + (row * 8 + s1_) * 8);
      oa[nt2] = mfma16(pf0a, vf0, oa[nt2]);
      oa[nt2] = mfma16(pf1a, vf1, oa[nt2]);
      ob[nt2] = mfma16(pf0b, vf0, ob[nt2]);
      ob[nt2] = mfma16(pf1b, vf1, ob[nt2]);
    }
  }

  // write unnormalized partials + l; each wave owns its 32 rows
  float* dst = (z == 0) ? o0g : (po5 + (size_t)(z - 1) * 4 * 4096 * 64);
#pragma unroll
  for (int nt2 = 0; nt2 < 4; nt2++)
#pragma unroll
    for (int reg = 0; reg < 4; reg++) {
      int ra = qw + quad * 4 + reg;
      dst[((size_t)b * 4096 + ra) * 64 + nt2 * 16 + ln] = oa[nt2][reg];
      dst[((size_t)b * 4096 + ra + 16) * 64 + nt2 * 16 + ln] = ob[nt2][reg];
    }
  if (ln == 0) {
#pragma unroll
    for (int reg = 0; reg < 4; reg++) {
      int ra = qw + quad * 4 + reg;
      mlb[((size_t)z * 4 + b) * 4096 + ra] = la[reg];
      mlb[((size_t)z * 4 + b) * 4096 + ra + 16] = lb[reg];
    }
  }
}

// ---------------- merge the six split-K parts: out = Σo_z / Σl_z
__global__ __launch_bounds__(256) void merge_kernel(float* __restrict__ out,
                                                    const float* __restrict__ po5,
                                                    const float* __restrict__ mlb) {
  int qt = blockIdx.x, b = blockIdx.y;
  int r = threadIdx.x >> 3;
  int c = (threadIdx.x & 7) * 8;
  size_t row = (size_t)b * 4096 + qt * 32 + r;
  float l = mlb[row];
#pragma unroll
  for (int z = 1; z < 6; z++) l += mlb[(size_t)z * 4 * 4096 + row];
  float inv = 1.0f / l;
  float* op = out + row * 64 + c;
  fx4 u0 = *(fx4*)op, u1 = *(fx4*)(op + 4);
#pragma unroll
  for (int z = 1; z < 6; z++) {
    const float* pp = po5 + (size_t)(z - 1) * 4 * 4096 * 64 + row * 64 + c;
    fx4 v0 = *(const fx4*)pp, v1 = *(const fx4*)(pp + 4);
#pragma unroll
    for (int j = 0; j < 4; j++) { u0[j] += v0[j]; u1[j] += v1[j]; }
  }
#pragma unroll
  for (int j = 0; j < 4; j++) { u0[j] *= inv; u1[j] *= inv; }
  *(fx4*)op = u0;
  *(fx4*)(op + 4) = u1;
}

extern "C" void kernel_launch(void* const* d_in, const int* in_sizes, int n_in,
                              void* d_out, int out_size, void* d_ws, size_t ws_size,
                              hipStream_t stream) {
  const float* x  = (const float*)d_in[0];
  const float* Wq = (const float*)d_in[1];
  const float* Wk = (const float*)d_in[2];
  const float* Wv = (const float*)d_in[3];

  u16* qbw = (u16*)d_ws;                          // [16384][64] bf16, 2MB
  u16* kbw = qbw + (size_t)TOKENS * 64;           // 2MB
  u16* vtw = kbw + (size_t)TOKENS * 64;           // 2MB
  u16* wfr = vtw + (size_t)TOKENS * 64;           // 288KB
  float* po5 = (float*)(wfr + (size_t)3 * KSTEPS * 256 * 8);  // 5x [4][4096][64] fp32, 20MB
  float* mlb = po5 + (size_t)5 * 4 * 4096 * 64;   // [6][4][4096] float, 384KB

  prep_w_kernel<<<72, 256, 0, stream>>>(Wq, Wk, Wv, wfr);
  proj_kernel<<<TOKENS / 32, 256, 0, stream>>>(x, wfr, qbw, kbw, vtw);
  attn_kernel<<<dim3(32, 4, 6), 256, 0, stream>>>(qbw, kbw, vtw,
                                                  (float*)d_out, po5, mlb);
  merge_kernel<<<dim3(128, 4), 256, 0, stream>>>((float*)d_out, po5, mlb);
}